// Round 1
// baseline (422.132 us; speedup 1.0000x reference)
//
#include <hip/hip_runtime.h>
#include <hip/hip_bf16.h>

#define N_NODES 20000
#define B 4
#define H 128
#define I_DIM 64
#define E_MAX 320000

// ---- all scratch in module-static device globals (no d_ws dependence) ----
__device__ int   g_deg_src[N_NODES];
__device__ int   g_deg_dst[N_NODES];
__device__ int   g_offsets[N_NODES + 1];
__device__ int   g_cursor[N_NODES];
__device__ int   g_csr[E_MAX];
__device__ float g_dn_src[N_NODES];
__device__ float g_dn_dst[N_NODES];
__device__ float g_xg[4 * B * H];
// batch-interleaved bf16 copy of h_prev, pre-scaled by dn_src:
// g_hs[n*H+h] = {bf16 (h_prev[b][n][h] * dn_src[n]), b=0..3}
__device__ uint2 g_hs[N_NODES * H];

// ---- phase 0: zero the degree counters (re-run safe across launches) ----
__global__ void zero_kernel() {
    int i = blockIdx.x * blockDim.x + threadIdx.x;
    if (i < N_NODES) { g_deg_src[i] = 0; g_deg_dst[i] = 0; }
}

// ---- phase 1: global-atomic degree histograms (L2-resident 80KB tables,
//               avg 16 hits/counter -> negligible contention, full-chip grid) ----
__global__ void degree_kernel(const int* __restrict__ src,
                              const int* __restrict__ dst, int E) {
    int e = blockIdx.x * blockDim.x + threadIdx.x;
    if (e < E) {
        atomicAdd(&g_deg_dst[dst[e]], 1);
        atomicAdd(&g_deg_src[src[e]], 1);
    }
}

// ---- phase 2: single-block exclusive scan -> offsets, cursor copy, dn factors ----
__global__ void scan_kernel() {
    __shared__ int sums[256];
    int t = threadIdx.x;
    const int CH = (N_NODES + 255) / 256;     // 79
    int lo = t * CH;
    int hi = lo + CH; if (hi > N_NODES) hi = N_NODES;
    int s = 0;
    for (int i = lo; i < hi; i++) s += g_deg_dst[i];
    sums[t] = s;
    __syncthreads();
    if (t == 0) {
        int run = 0;
        for (int i = 0; i < 256; i++) { int v = sums[i]; sums[i] = run; run += v; }
        g_offsets[N_NODES] = run;
    }
    __syncthreads();
    int run = sums[t];
    for (int i = lo; i < hi; i++) {
        g_offsets[i] = run;
        g_cursor[i]  = run;
        int dd = g_deg_dst[i];
        run += dd;
        g_dn_dst[i] = rsqrtf(fmaxf((float)dd, 1.0f));
        g_dn_src[i] = rsqrtf(fmaxf((float)g_deg_src[i], 1.0f));
    }
}

// ---- phase 3: placement via global-atomic cursor (rank order arbitrary;
//               fp32 sum re-association noise ~1e-6, far under tolerance) ----
__global__ void place_kernel(const int* __restrict__ src,
                             const int* __restrict__ dst, int E) {
    int e = blockIdx.x * blockDim.x + threadIdx.x;
    if (e < E) {
        int d = dst[e];
        int slot = atomicAdd(&g_cursor[d], 1);
        g_csr[slot] = src[e];
    }
}

// -------- pack h_prev * dn_src into batch-interleaved bf16 --------
// (bf16(h*sc) has the same 2^-9 relative error as bf16(h)*sc; folding removes
//  the per-edge dn_src load + 4 muls from the latency-critical gather loop)
__global__ void pack_kernel(const float* __restrict__ h_prev) {
    int i = blockIdx.x * blockDim.x + threadIdx.x;   // (n*H + h)
    if (i >= N_NODES * H) return;
    int n = i >> 7;                                   // H = 128
    float sc = g_dn_src[n];
    const long stride = (long)N_NODES * H;
    float v0 = h_prev[i] * sc;
    float v1 = h_prev[i + stride] * sc;
    float v2 = h_prev[i + 2 * stride] * sc;
    float v3 = h_prev[i + 3 * stride] * sc;
    __hip_bfloat162 p01 = __float22bfloat162_rn(make_float2(v0, v1));
    __hip_bfloat162 p23 = __float22bfloat162_rn(make_float2(v2, v3));
    uint2 w;
    w.x = *reinterpret_cast<unsigned int*>(&p01);
    w.y = *reinterpret_cast<unsigned int*>(&p23);
    g_hs[i] = w;
}

// ---------------- xg[g][b][h] = x[b,:] @ W_g + b_g  (fp32) ----------------
__global__ void xgate_kernel(const float* __restrict__ x,
                             const float* __restrict__ Wi, const float* __restrict__ bi,
                             const float* __restrict__ Wf, const float* __restrict__ bf_,
                             const float* __restrict__ Wo, const float* __restrict__ bo,
                             const float* __restrict__ Wc, const float* __restrict__ bc) {
    int g = blockIdx.x >> 2;   // gate 0..3 (i,f,o,c)
    int b = blockIdx.x & 3;
    int h = threadIdx.x;
    const float* W;
    const float* bb;
    switch (g) {
        case 0: W = Wi; bb = bi; break;
        case 1: W = Wf; bb = bf_; break;
        case 2: W = Wo; bb = bo; break;
        default: W = Wc; bb = bc; break;
    }
    float acc = bb[h];
#pragma unroll
    for (int i = 0; i < I_DIM; i++)
        acc += x[b * I_DIM + i] * W[i * H + h];
    g_xg[(g * B + b) * H + h] = acc;
}

__device__ __forceinline__ float fast_sigmoid(float z) {
    return 1.f / (1.f + __expf(-z));
}
__device__ __forceinline__ float fast_tanh(float z) {
    // 1 - 2/(e^{2z}+1): e^{2z}->inf => 1; e^{2z}->0 => -1. No inf/inf NaN path.
    return 1.f - 2.f / (__expf(2.f * z) + 1.f);
}

// ------- fused: CSR gather (bf16 table) + Wg matvec + gates + LSTM ---------
__global__ __launch_bounds__(128)
void fused_kernel(const float* __restrict__ Wg, const float* __restrict__ bg,
                  const float* __restrict__ c_prev,
                  float* __restrict__ out_h, float* __restrict__ out_c) {
    int n = blockIdx.x;
    int h = threadIdx.x;
    int beg = g_offsets[n];
    int end = g_offsets[n + 1];

    float a0 = 0.f, a1 = 0.f, a2 = 0.f, a3 = 0.f;

#define ACC(w) { \
        __hip_bfloat162 p01 = *reinterpret_cast<__hip_bfloat162*>(&(w).x); \
        __hip_bfloat162 p23 = *reinterpret_cast<__hip_bfloat162*>(&(w).y); \
        float2 f01 = __bfloat1622float2(p01); \
        float2 f23 = __bfloat1622float2(p23); \
        a0 += f01.x; a1 += f01.y; a2 += f23.x; a3 += f23.y; }

    // 4-wide manual unroll: issue 4 csr loads, then 4 independent g_hs row
    // loads, THEN consume -> 4x memory-level parallelism vs the 2-deep
    // dependent chain the compiler produced for the unknown-trip-count loop.
    int j = beg;
    for (; j + 4 <= end; j += 4) {
        int s0 = g_csr[j];
        int s1 = g_csr[j + 1];
        int s2 = g_csr[j + 2];
        int s3 = g_csr[j + 3];
        uint2 w0 = g_hs[s0 * H + h];
        uint2 w1 = g_hs[s1 * H + h];
        uint2 w2 = g_hs[s2 * H + h];
        uint2 w3 = g_hs[s3 * H + h];
        ACC(w0); ACC(w1); ACC(w2); ACC(w3);
    }
    for (; j < end; j++) {
        int s = g_csr[j];
        uint2 w = g_hs[s * H + h];
        ACC(w);
    }
#undef ACC

    float dd = g_dn_dst[n];

    __shared__ float4 arow4[H];
    arow4[h] = make_float4(a0 * dd, a1 * dd, a2 * dd, a3 * dd);
    __syncthreads();

    float g0 = 0.f, g1 = 0.f, g2 = 0.f, g3 = 0.f;
#pragma unroll 8
    for (int k = 0; k < H; k++) {
        float w = Wg[k * H + h];               // coalesced, L1/L2-resident
        float4 a = arow4[k];                   // one ds_read_b128, broadcast
        g0 += a.x * w;
        g1 += a.y * w;
        g2 += a.z * w;
        g3 += a.w * w;
    }
    float bgh = bg[h];

    const long stride = (long)N_NODES * H;
    float gh_arr[B] = {g0 + bgh, g1 + bgh, g2 + bgh, g3 + bgh};
#pragma unroll
    for (int b = 0; b < B; b++) {
        float gh = gh_arr[b];
        float xi = g_xg[(0 * B + b) * H + h];
        float xf = g_xg[(1 * B + b) * H + h];
        float xo = g_xg[(2 * B + b) * H + h];
        float xc = g_xg[(3 * B + b) * H + h];

        float it = fast_sigmoid(xi + gh);
        float ft = fast_sigmoid(xf + gh);
        float ot = fast_sigmoid(xo + gh);
        float ct = fast_tanh(xc + gh);

        long idx = (long)b * stride + (long)n * H + h;
        float cp = c_prev[idx];
        float c  = ft * cp + it * ct;
        float ho = ot * fast_tanh(c);

        out_h[idx] = ho;
        out_c[idx] = c;
    }
}

extern "C" void kernel_launch(void* const* d_in, const int* in_sizes, int n_in,
                              void* d_out, int out_size, void* d_ws, size_t ws_size,
                              hipStream_t stream) {
    const float* x      = (const float*)d_in[0];
    const float* h_prev = (const float*)d_in[1];
    const float* c_prev = (const float*)d_in[2];
    const int* src = (const int*)d_in[3];
    const int* dst = (const int*)d_in[4];
    const float* Wi = (const float*)d_in[5];
    const float* bi = (const float*)d_in[6];
    const float* Wf = (const float*)d_in[7];
    const float* bf_ = (const float*)d_in[8];
    const float* Wo = (const float*)d_in[9];
    const float* bo = (const float*)d_in[10];
    const float* Wc = (const float*)d_in[11];
    const float* bc = (const float*)d_in[12];
    const float* Wg = (const float*)d_in[13];
    const float* bg = (const float*)d_in[14];

    int E = in_sizes[3];
    if (E > E_MAX) E = E_MAX;   // static scratch bound (setup fixes E=320000)
    int eb = (E + 255) / 256;
    int nb = (N_NODES + 255) / 256;

    zero_kernel<<<nb, 256, 0, stream>>>();
    degree_kernel<<<eb, 256, 0, stream>>>(src, dst, E);
    scan_kernel<<<1, 256, 0, stream>>>();
    pack_kernel<<<(N_NODES * H + 255) / 256, 256, 0, stream>>>(h_prev);
    place_kernel<<<eb, 256, 0, stream>>>(src, dst, E);
    xgate_kernel<<<16, H, 0, stream>>>(x, Wi, bi, Wf, bf_, Wo, bo, Wc, bc);

    float* out_h = (float*)d_out;
    float* out_c = out_h + (long)B * N_NODES * H;
    fused_kernel<<<N_NODES, H, 0, stream>>>(Wg, bg, c_prev, out_h, out_c);
}

// Round 2
// 368.808 us; speedup vs baseline: 1.1446x; 1.1446x over previous
//
#include <hip/hip_runtime.h>
#include <hip/hip_bf16.h>

#define N_NODES 20000
#define B 4
#define H 128
#define I_DIM 64
#define E_MAX 320000

// ---- all scratch in module-static device globals (no d_ws dependence) ----
// g_deg_* are zeroed by fused_kernel's epilogue each run (zero-init at load),
// so no standalone zero kernel is needed.
__device__ int   g_deg_src[N_NODES];
__device__ int   g_deg_dst[N_NODES];
__device__ int   g_offsets[N_NODES + 1];
__device__ int   g_cursor[N_NODES];
__device__ int   g_csr[E_MAX];
__device__ float g_dn_src[N_NODES];
__device__ float g_dn_dst[N_NODES];
__device__ float g_xg[4 * B * H];
// batch-interleaved bf16 copy of h_prev, pre-scaled by dn_src:
// g_hs[n*H+h] = {bf16 (h_prev[b][n][h] * dn_src[n]), b=0..3}
__device__ uint2 g_hs[N_NODES * H];

// ---- phase 1: global-atomic degree histograms (L2-resident 80KB tables) ----
__global__ __launch_bounds__(256)
void degree_kernel(const int* __restrict__ src,
                   const int* __restrict__ dst, int E) {
    int e = blockIdx.x * blockDim.x + threadIdx.x;
    if (e < E) {
        atomicAdd(&g_deg_dst[dst[e]], 1);
        atomicAdd(&g_deg_src[src[e]], 1);
    }
}

// ---- phase 2: single-block scan, 1024 threads, shfl + LDS wave combine ----
__global__ __launch_bounds__(1024)
void scan_kernel() {
    __shared__ int wsum[16];
    int t = threadIdx.x;
    const int CH = (N_NODES + 1023) / 1024;   // 20
    int lo = t * CH;
    int hi = lo + CH; if (hi > N_NODES) hi = N_NODES;
    int s = 0;
    for (int i = lo; i < hi; i++) s += g_deg_dst[i];

    // inclusive shfl scan within wave (64 lanes)
    int lane = t & 63, w = t >> 6;
    int inc = s;
    for (int d = 1; d < 64; d <<= 1) {
        int v = __shfl_up(inc, d);
        if (lane >= d) inc += v;
    }
    if (lane == 63) wsum[w] = inc;
    __syncthreads();
    if (t == 0) {
        int run = 0;
        for (int i = 0; i < 16; i++) { int v = wsum[i]; wsum[i] = run; run += v; }
        g_offsets[N_NODES] = run;
    }
    __syncthreads();

    int run = wsum[w] + inc - s;              // exclusive prefix for this thread
    for (int i = lo; i < hi; i++) {
        g_offsets[i] = run;
        g_cursor[i]  = run;
        int dd = g_deg_dst[i];
        run += dd;
        g_dn_dst[i] = rsqrtf(fmaxf((float)dd, 1.0f));
        g_dn_src[i] = rsqrtf(fmaxf((float)g_deg_src[i], 1.0f));
    }
}

// ---- phase 3 (merged): pack + place + xgate, block-range dispatched ----
// pack:  blocks [0, 10000)          — h_prev * dn_src -> bf16 x4 batches
// place: blocks [10000, 10000+eb)   — CSR scatter via atomic cursor
// xgate: blocks [10000+eb, +8)      — x @ W_g + b_g for 4 gates x 4 batches
__global__ __launch_bounds__(256)
void mid_kernel(const float* __restrict__ h_prev,
                const int* __restrict__ src, const int* __restrict__ dst, int E,
                int place_blocks,
                const float* __restrict__ x,
                const float* __restrict__ Wi, const float* __restrict__ bi,
                const float* __restrict__ Wf, const float* __restrict__ bf_,
                const float* __restrict__ Wo, const float* __restrict__ bo,
                const float* __restrict__ Wc, const float* __restrict__ bc) {
    const int PACK_BLKS = (N_NODES * H) / 256;   // 10000, exact
    int blk = blockIdx.x;
    int t = threadIdx.x;

    if (blk < PACK_BLKS) {
        int i = blk * 256 + t;                    // (n*H + h), always in range
        int n = i >> 7;                           // H = 128
        float sc = g_dn_src[n];
        const long stride = (long)N_NODES * H;
        float v0 = h_prev[i] * sc;
        float v1 = h_prev[i + stride] * sc;
        float v2 = h_prev[i + 2 * stride] * sc;
        float v3 = h_prev[i + 3 * stride] * sc;
        __hip_bfloat162 p01 = __float22bfloat162_rn(make_float2(v0, v1));
        __hip_bfloat162 p23 = __float22bfloat162_rn(make_float2(v2, v3));
        uint2 wv;
        wv.x = *reinterpret_cast<unsigned int*>(&p01);
        wv.y = *reinterpret_cast<unsigned int*>(&p23);
        g_hs[i] = wv;
    } else if (blk < PACK_BLKS + place_blocks) {
        int e = (blk - PACK_BLKS) * 256 + t;
        if (e < E) {
            int d = dst[e];
            int slot = atomicAdd(&g_cursor[d], 1);
            g_csr[slot] = src[e];
        }
    } else {
        int bid = blk - PACK_BLKS - place_blocks; // 0..7
        int g = bid >> 1;                         // gate 0..3
        int b = ((bid & 1) << 1) | (t >> 7);      // batch 0..3
        int h = t & 127;
        const float* W;
        const float* bb;
        switch (g) {
            case 0: W = Wi; bb = bi; break;
            case 1: W = Wf; bb = bf_; break;
            case 2: W = Wo; bb = bo; break;
            default: W = Wc; bb = bc; break;
        }
        float acc = bb[h];
#pragma unroll
        for (int i = 0; i < I_DIM; i++)
            acc += x[b * I_DIM + i] * W[i * H + h];
        g_xg[(g * B + b) * H + h] = acc;
    }
}

__device__ __forceinline__ float fast_sigmoid(float z) {
    return 1.f / (1.f + __expf(-z));
}
__device__ __forceinline__ float fast_tanh(float z) {
    // 1 - 2/(e^{2z}+1): e^{2z}->inf => 1; e^{2z}->0 => -1. No inf/inf NaN path.
    return 1.f - 2.f / (__expf(2.f * z) + 1.f);
}

// ------- fused: CSR gather (bf16 table) + Wg matvec + gates + LSTM ---------
__global__ __launch_bounds__(128)
void fused_kernel(const float* __restrict__ Wg, const float* __restrict__ bg,
                  const float* __restrict__ c_prev,
                  float* __restrict__ out_h, float* __restrict__ out_c) {
    int n = blockIdx.x;
    int h = threadIdx.x;
    int beg = g_offsets[n];
    int end = g_offsets[n + 1];

    float a0 = 0.f, a1 = 0.f, a2 = 0.f, a3 = 0.f;

#define ACC(w) { \
        __hip_bfloat162 p01 = *reinterpret_cast<__hip_bfloat162*>(&(w).x); \
        __hip_bfloat162 p23 = *reinterpret_cast<__hip_bfloat162*>(&(w).y); \
        float2 f01 = __bfloat1622float2(p01); \
        float2 f23 = __bfloat1622float2(p23); \
        a0 += f01.x; a1 += f01.y; a2 += f23.x; a3 += f23.y; }

    // 8-wide manual unroll: 8 csr loads then 8 independent g_hs row loads in
    // flight before any consumption -> 8x memory-level parallelism on the
    // latency-critical random gather (avg degree 16 => two full groups).
    int j = beg;
    for (; j + 8 <= end; j += 8) {
        int s0 = g_csr[j];
        int s1 = g_csr[j + 1];
        int s2 = g_csr[j + 2];
        int s3 = g_csr[j + 3];
        int s4 = g_csr[j + 4];
        int s5 = g_csr[j + 5];
        int s6 = g_csr[j + 6];
        int s7 = g_csr[j + 7];
        uint2 w0 = g_hs[s0 * H + h];
        uint2 w1 = g_hs[s1 * H + h];
        uint2 w2 = g_hs[s2 * H + h];
        uint2 w3 = g_hs[s3 * H + h];
        uint2 w4 = g_hs[s4 * H + h];
        uint2 w5 = g_hs[s5 * H + h];
        uint2 w6 = g_hs[s6 * H + h];
        uint2 w7 = g_hs[s7 * H + h];
        ACC(w0); ACC(w1); ACC(w2); ACC(w3);
        ACC(w4); ACC(w5); ACC(w6); ACC(w7);
    }
    for (; j + 4 <= end; j += 4) {
        int s0 = g_csr[j];
        int s1 = g_csr[j + 1];
        int s2 = g_csr[j + 2];
        int s3 = g_csr[j + 3];
        uint2 w0 = g_hs[s0 * H + h];
        uint2 w1 = g_hs[s1 * H + h];
        uint2 w2 = g_hs[s2 * H + h];
        uint2 w3 = g_hs[s3 * H + h];
        ACC(w0); ACC(w1); ACC(w2); ACC(w3);
    }
    for (; j < end; j++) {
        int s = g_csr[j];
        uint2 w = g_hs[s * H + h];
        ACC(w);
    }
#undef ACC

    float dd = g_dn_dst[n];

    __shared__ float4 arow4[H];
    arow4[h] = make_float4(a0 * dd, a1 * dd, a2 * dd, a3 * dd);
    __syncthreads();

    float g0 = 0.f, g1 = 0.f, g2 = 0.f, g3 = 0.f;
#pragma unroll 8
    for (int k = 0; k < H; k++) {
        float w = Wg[k * H + h];               // coalesced, L1/L2-resident
        float4 a = arow4[k];                   // broadcast ds_read
        g0 += a.x * w;
        g1 += a.y * w;
        g2 += a.z * w;
        g3 += a.w * w;
    }
    float bgh = bg[h];

    const long stride = (long)N_NODES * H;
    float gh_arr[B] = {g0 + bgh, g1 + bgh, g2 + bgh, g3 + bgh};
#pragma unroll
    for (int b = 0; b < B; b++) {
        float gh = gh_arr[b];
        float xi = g_xg[(0 * B + b) * H + h];
        float xf = g_xg[(1 * B + b) * H + h];
        float xo = g_xg[(2 * B + b) * H + h];
        float xc = g_xg[(3 * B + b) * H + h];

        float it = fast_sigmoid(xi + gh);
        float ft = fast_sigmoid(xf + gh);
        float ot = fast_sigmoid(xo + gh);
        float ct = fast_tanh(xc + gh);

        long idx = (long)b * stride + (long)n * H + h;
        float cp = c_prev[idx];
        float c  = ft * cp + it * ct;
        float ho = ot * fast_tanh(c);

        out_h[idx] = ho;
        out_c[idx] = c;
    }

    // zero degree counters for the next run (grid == N_NODES exactly);
    // device globals are zero-init at module load, so run 0 is also correct.
    if (h == 0) {
        g_deg_dst[n] = 0;
        g_deg_src[n] = 0;
    }
}

extern "C" void kernel_launch(void* const* d_in, const int* in_sizes, int n_in,
                              void* d_out, int out_size, void* d_ws, size_t ws_size,
                              hipStream_t stream) {
    const float* x      = (const float*)d_in[0];
    const float* h_prev = (const float*)d_in[1];
    const float* c_prev = (const float*)d_in[2];
    const int* src = (const int*)d_in[3];
    const int* dst = (const int*)d_in[4];
    const float* Wi = (const float*)d_in[5];
    const float* bi = (const float*)d_in[6];
    const float* Wf = (const float*)d_in[7];
    const float* bf_ = (const float*)d_in[8];
    const float* Wo = (const float*)d_in[9];
    const float* bo = (const float*)d_in[10];
    const float* Wc = (const float*)d_in[11];
    const float* bc = (const float*)d_in[12];
    const float* Wg = (const float*)d_in[13];
    const float* bg = (const float*)d_in[14];

    int E = in_sizes[3];
    if (E > E_MAX) E = E_MAX;   // static scratch bound (setup fixes E=320000)
    int eb = (E + 255) / 256;
    const int PACK_BLKS = (N_NODES * H) / 256;   // 10000

    degree_kernel<<<eb, 256, 0, stream>>>(src, dst, E);
    scan_kernel<<<1, 1024, 0, stream>>>();
    mid_kernel<<<PACK_BLKS + eb + 8, 256, 0, stream>>>(
        h_prev, src, dst, E, eb,
        x, Wi, bi, Wf, bf_, Wo, bo, Wc, bc);

    float* out_h = (float*)d_out;
    float* out_c = out_h + (long)B * N_NODES * H;
    fused_kernel<<<N_NODES, 128, 0, stream>>>(Wg, bg, c_prev, out_h, out_c);
}